// Round 9
// baseline (583.269 us; speedup 1.0000x reference)
//
#include <hip/hip_runtime.h>

#define NN 50000
#define NE 800000
#define DD 128
#define NG 250
#define BN_EPS 1e-5f
#define ELLW 64
#define GATHER_BLOCKS 4096

typedef unsigned short u16;
typedef __attribute__((ext_vector_type(8))) short bf16x8;
typedef __attribute__((ext_vector_type(4))) float f32x4;

__device__ inline u16 f2bf(float f) {
    union { float f; unsigned u; } c;
    c.f = f;
    unsigned r = c.u + 0x7fffu + ((c.u >> 16) & 1u);  // RTNE
    return (u16)(r >> 16);
}
__device__ inline float bf2f(u16 h) {
    union { unsigned u; float f; } c;
    c.u = (unsigned)h << 16;
    return c.f;
}
__device__ inline unsigned pack2bf(float lo, float hi) {
    return (unsigned)f2bf(lo) | ((unsigned)f2bf(hi) << 16);
}
__device__ inline float bf_lo(unsigned u) {
    union { unsigned u; float f; } c;
    c.u = u << 16;
    return c.f;
}
__device__ inline float bf_hi(unsigned u) {
    union { unsigned u; float f; } c;
    c.u = u & 0xffff0000u;
    return c.f;
}

// ---------------- ELL build ----------------

__global__ void fillell_k(const int* __restrict__ src, const int* __restrict__ dst,
                          int* __restrict__ fc, u16* __restrict__ ell) {
    int e = blockIdx.x * 256 + threadIdx.x;
    if (e < NE) {
        int d = dst[e];
        int pos = atomicAdd(&fc[d], 1);
        if (pos < ELLW) ell[(size_t)d * ELLW + pos] = (u16)src[e];
    }
}

__global__ void dis_k(const int* __restrict__ fc, float* __restrict__ dis) {
    int i = blockIdx.x * 256 + threadIdx.x;
    if (i < NN) dis[i] = 1.0f / sqrtf((float)(fc[i] + 1));
}

// ---------------- W prep: W(fp32 [k][n]) -> WhiT,WloT (bf16 [n][k]) ----------------

__global__ void wprep_k(const float* __restrict__ W1, const float* __restrict__ W2,
                        const float* __restrict__ W3, u16* __restrict__ wt) {
    int lid = blockIdx.x >> 6;                       // layer 0..2
    int idx = (blockIdx.x & 63) * 256 + threadIdx.x; // 0..16383
    const float* W = lid == 0 ? W1 : (lid == 1 ? W2 : W3);
    int k = idx >> 7, n = idx & 127;
    float w = W[idx];
    u16 hi = f2bf(w);
    u16 lo = f2bf(w - bf2f(hi));
    wt[((size_t)lid * 2 + 0) * 16384 + (size_t)n * 128 + k] = hi;
    wt[((size_t)lid * 2 + 1) * 16384 + (size_t)n * 128 + k] = lo;
}

// ---------------- MFMA GEMM: HB(bf16) = dis[row] * (act(A) @ (Whi+Wlo)) ----------------
// 16x16x32 bf16 MFMA. A: row=lane&15, k=(lane>>4)*8+j. B: col=lane&15, same k.
// D: col=lane&15, row=(lane>>4)*4+reg.  BM=64 (4 waves x 16 rows), BN=128.
// W staged in LDS (64KB) with XOR swizzle byte^=((n&7)<<4) to kill the
// 16-way bank conflict of stride-256B col reads (->2-way, free).

__global__ __launch_bounds__(256) void mgemm_k(const float* __restrict__ A32,
                                               const u16* __restrict__ A16,
                                               const u16* __restrict__ WT,  // [2][128][128]
                                               const float* __restrict__ sc,
                                               const float* __restrict__ sh,
                                               const float* __restrict__ dis,
                                               u16* __restrict__ HB, int use_bn) {
    __shared__ u16 WL[2 * 128 * 128];   // 64KB
    __shared__ float scs[128], shs[128];
    int tid = threadIdx.x;
    if (use_bn && tid < 128) { scs[tid] = sc[tid]; shs[tid] = sh[tid]; }
    // stage W (both halves) with swizzle
    {
        const uint4* wg = (const uint4*)WT;
#pragma unroll
        for (int i = 0; i < 16; i++) {
            int ci = tid + i * 256;                  // 4096 chunks of 16B
            unsigned byte = (unsigned)ci * 16;
            unsigned n = (byte >> 8) & 127;
            unsigned swz = byte ^ ((n & 7) << 4);
            *(uint4*)((char*)WL + swz) = wg[ci];
        }
    }
    __syncthreads();

    int w = tid >> 6, lane = tid & 63;
    int col = lane & 15, lg = lane >> 4;
    int rowA = blockIdx.x * 64 + w * 16 + col;

    union { uint4 q; bf16x8 v; } afr[4];
#pragma unroll
    for (int s = 0; s < 4; s++) afr[s].q = make_uint4(0, 0, 0, 0);
    if (rowA < NN) {
        if (!use_bn) {  // layer 1: fp32 input, convert inline
            const float4* ap = (const float4*)(A32 + (size_t)rowA * DD);
#pragma unroll
            for (int s = 0; s < 4; s++) {
                float4 f0 = ap[s * 8 + lg * 2];
                float4 f1 = ap[s * 8 + lg * 2 + 1];
                afr[s].q = make_uint4(pack2bf(f0.x, f0.y), pack2bf(f0.z, f0.w),
                                      pack2bf(f1.x, f1.y), pack2bf(f1.z, f1.w));
            }
        } else {
            const uint4* ap = (const uint4*)(A16 + (size_t)rowA * DD);
#pragma unroll
            for (int s = 0; s < 4; s++) {
                uint4 q = ap[s * 4 + lg];
                unsigned uu[4] = {q.x, q.y, q.z, q.w};
                int cbase = s * 32 + lg * 8;
#pragma unroll
                for (int t = 0; t < 4; t++) {
                    int c0 = cbase + t * 2;
                    float f0 = fmaxf(fmaf(bf_lo(uu[t]), scs[c0], shs[c0]), 0.f);
                    float f1 = fmaxf(fmaf(bf_hi(uu[t]), scs[c0 + 1], shs[c0 + 1]), 0.f);
                    uu[t] = pack2bf(f0, f1);
                }
                afr[s].q = make_uint4(uu[0], uu[1], uu[2], uu[3]);
            }
        }
    }

    f32x4 acc[8];
#pragma unroll
    for (int cf = 0; cf < 8; cf++) { acc[cf][0] = 0.f; acc[cf][1] = 0.f; acc[cf][2] = 0.f; acc[cf][3] = 0.f; }

#pragma unroll
    for (int half = 0; half < 2; half++) {
#pragma unroll
        for (int s = 0; s < 4; s++) {
#pragma unroll
            for (int cf = 0; cf < 8; cf++) {
                int nn = cf * 16 + col;
                unsigned byte = (unsigned)half * 32768 + (unsigned)nn * 256
                              + (unsigned)(s * 64 + lg * 16);
                byte ^= ((nn & 7) << 4);
                bf16x8 b = *(const bf16x8*)((const char*)WL + byte);
                acc[cf] = __builtin_amdgcn_mfma_f32_16x16x32_bf16(afr[s].v, b, acc[cf], 0, 0, 0);
            }
        }
    }

#pragma unroll
    for (int r = 0; r < 4; r++) {
        int ro = blockIdx.x * 64 + w * 16 + lg * 4 + r;
        if (ro < NN) {
            float dv = dis[ro];
#pragma unroll
            for (int cf = 0; cf < 8; cf++) {
                HB[(size_t)ro * DD + cf * 16 + col] = f2bf(acc[cf][r] * dv);
            }
        }
    }
}

// ---------------- Gather (ELL, pre-scaled bf16 rows) + self-loop + bias + BN stats ----------------

__global__ __launch_bounds__(256) void gather_k(const u16* __restrict__ HB,
                                                const float* __restrict__ dis,
                                                const int* __restrict__ fc,
                                                const u16* __restrict__ ell,
                                                const float* __restrict__ bias,
                                                u16* __restrict__ AGG,
                                                float* __restrict__ stats) {
    __shared__ float s_sum[128], s_sq[128];
    int tid = threadIdx.x;
    if (tid < 128) { s_sum[tid] = 0.f; s_sq[tid] = 0.f; }
    __syncthreads();
    int lane = tid & 63;
    int wid = blockIdx.x * 4 + (tid >> 6);
    const int nwaves = GATHER_BLOCKS * 4;
    int c = lane * 2;
    float b0 = bias[c], b1 = bias[c + 1];
    float lsum0 = 0.f, lsum1 = 0.f, lsq0 = 0.f, lsq1 = 0.f;
    for (int v = wid; v < NN; v += nwaves) {
        int cntv = fc[v];
        if (cntv > ELLW) cntv = ELLW;
        int myidx = (lane < cntv) ? (int)ell[(size_t)v * ELLW + lane] : 0;
        float a0 = 0.f, a1 = 0.f;
        int j = 0;
        for (; j + 8 <= cntv; j += 8) {
            unsigned r[8];
#pragma unroll
            for (int q = 0; q < 8; q++) {
                int s = __shfl(myidx, j + q);
                r[q] = *(const unsigned*)(HB + (size_t)s * DD + c);
            }
#pragma unroll
            for (int q = 0; q < 8; q++) { a0 += bf_lo(r[q]); a1 += bf_hi(r[q]); }
        }
        for (; j < cntv; j++) {
            int s = __shfl(myidx, j);
            unsigned r0 = *(const unsigned*)(HB + (size_t)s * DD + c);
            a0 += bf_lo(r0);
            a1 += bf_hi(r0);
        }
        unsigned rsf = *(const unsigned*)(HB + (size_t)v * DD + c);
        float dv = dis[v];
        float o0 = fmaf(a0 + bf_lo(rsf), dv, b0);
        float o1 = fmaf(a1 + bf_hi(rsf), dv, b1);
        *(unsigned*)(AGG + (size_t)v * DD + c) = pack2bf(o0, o1);
        lsum0 += o0; lsum1 += o1;
        lsq0 += o0 * o0; lsq1 += o1 * o1;
    }
    atomicAdd(&s_sum[c], lsum0);
    atomicAdd(&s_sum[c + 1], lsum1);
    atomicAdd(&s_sq[c], lsq0);
    atomicAdd(&s_sq[c + 1], lsq1);
    __syncthreads();
    if (tid < 128) {
        atomicAdd(&stats[tid], s_sum[tid]);
        atomicAdd(&stats[128 + tid], s_sq[tid]);
    }
}

// ---------------- BN stats -> scale/shift ----------------

__global__ void bnfix_k(const float* __restrict__ stats, const float* __restrict__ g,
                        const float* __restrict__ be, float* __restrict__ sc,
                        float* __restrict__ sh) {
    int c = threadIdx.x;
    float mean = stats[c] * (1.0f / NN);
    float var = stats[128 + c] * (1.0f / NN) - mean * mean;
    float s = g[c] / sqrtf(var + BN_EPS);
    sc[c] = s;
    sh[c] = be[c] - mean * s;
}

// ---------------- Pool (bf16 agg) ----------------

__global__ __launch_bounds__(256) void pool_k(const u16* __restrict__ AGG,
                                              const int* __restrict__ batch,
                                              const float* __restrict__ sc,
                                              const float* __restrict__ sh,
                                              float* __restrict__ P) {
    int lane = threadIdx.x & 63;
    int wid = blockIdx.x * 4 + (threadIdx.x >> 6);
    int nw = gridDim.x * 4;
    int c = lane * 2;
    float sc0 = sc[c], sc1 = sc[c + 1], sh0 = sh[c], sh1 = sh[c + 1];
    int chunk = (NN + nw - 1) / nw;
    int v0 = wid * chunk, v1 = v0 + chunk;
    if (v1 > NN) v1 = NN;
    if (v0 >= NN) return;
    int curb = batch[v0];
    float acc0 = 0.f, acc1 = 0.f;
    for (int v = v0; v < v1; v++) {
        int b = batch[v];
        if (b != curb) {
            atomicAdd(&P[curb * 128 + c], acc0);
            atomicAdd(&P[curb * 128 + c + 1], acc1);
            acc0 = 0.f; acc1 = 0.f; curb = b;
        }
        unsigned hv = *(const unsigned*)(AGG + (size_t)v * DD + c);
        acc0 += fmaxf(fmaf(bf_lo(hv), sc0, sh0), 0.f);
        acc1 += fmaxf(fmaf(bf_hi(hv), sc1, sh1), 0.f);
    }
    atomicAdd(&P[curb * 128 + c], acc0);
    atomicAdd(&P[curb * 128 + c + 1], acc1);
}

// ---------------- Head ----------------

__global__ __launch_bounds__(128) void head_k(const float* __restrict__ P,
                                              const float* __restrict__ Wm1,
                                              const float* __restrict__ bm1,
                                              const float* __restrict__ Wm2,
                                              const float* __restrict__ bm2,
                                              float* __restrict__ OUT) {
    __shared__ float prow[128];
    __shared__ float red[128];
    int g = blockIdx.x, t = threadIdx.x;
    prow[t] = P[g * 128 + t];
    __syncthreads();
    float acc = bm1[t];
#pragma unroll 8
    for (int i = 0; i < 128; i++) acc = fmaf(prow[i], Wm1[i * 128 + t], acc);
    red[t] = fmaxf(acc, 0.f) * Wm2[t];
    __syncthreads();
    for (int off = 64; off > 0; off >>= 1) {
        if (t < off) red[t] += red[t + off];
        __syncthreads();
    }
    if (t == 0) OUT[g] = red[0] + bm2[0];
}

// ---------------- Launch ----------------

extern "C" void kernel_launch(void* const* d_in, const int* in_sizes, int n_in,
                              void* d_out, int out_size, void* d_ws, size_t ws_size,
                              hipStream_t stream) {
    const float* x   = (const float*)d_in[0];
    const int*  ei   = (const int*)d_in[1];
    const int*  batch= (const int*)d_in[2];
    const float* W1  = (const float*)d_in[3];
    const float* b1  = (const float*)d_in[4];
    const float* g1  = (const float*)d_in[5];
    const float* be1 = (const float*)d_in[6];
    const float* W2  = (const float*)d_in[7];
    const float* b2  = (const float*)d_in[8];
    const float* g2  = (const float*)d_in[9];
    const float* be2 = (const float*)d_in[10];
    const float* W3  = (const float*)d_in[11];
    const float* b3  = (const float*)d_in[12];
    const float* g3  = (const float*)d_in[13];
    const float* be3 = (const float*)d_in[14];
    const float* Wm1 = (const float*)d_in[15];
    const float* bm1 = (const float*)d_in[16];
    const float* Wm2 = (const float*)d_in[17];
    const float* bm2 = (const float*)d_in[18];
    float* out = (float*)d_out;

    char* ws = (char*)d_ws;
    size_t off = 0;
    auto alloc = [&](size_t bytes) -> void* {
        void* p = ws + off;
        off = (off + bytes + 255) & ~(size_t)255;
        return p;
    };
    int*   fc    = (int*)alloc((size_t)NN * 4);
    float* dis   = (float*)alloc((size_t)NN * 4);
    u16*   ell   = (u16*)alloc((size_t)NN * ELLW * 2);
    u16*   hb    = (u16*)alloc((size_t)NN * DD * 2);
    u16*   agg   = (u16*)alloc((size_t)NN * DD * 2);
    u16*   wt    = (u16*)alloc((size_t)3 * 2 * 16384 * 2);
    float* stats = (float*)alloc(3 * 256 * 4);
    float* scb   = (float*)alloc(3 * 128 * 4);
    float* shb   = (float*)alloc(3 * 128 * 4);
    float* p     = (float*)alloc((size_t)NG * DD * 4);

    const int* srcI = ei;
    const int* dstI = ei + NE;

    hipMemsetAsync(fc, 0, (size_t)NN * 4, stream);
    hipMemsetAsync(stats, 0, 3 * 256 * 4, stream);
    hipMemsetAsync(p, 0, (size_t)NG * DD * 4, stream);

    fillell_k<<<(NE + 255) / 256, 256, 0, stream>>>(srcI, dstI, fc, ell);
    dis_k<<<(NN + 255) / 256, 256, 0, stream>>>(fc, dis);
    wprep_k<<<192, 256, 0, stream>>>(W1, W2, W3, wt);

    const int GB = (NN + 63) / 64;

    // Layer 1 (fp32 input converted inline)
    mgemm_k<<<GB, 256, 0, stream>>>(x, nullptr, wt, nullptr, nullptr, dis, hb, 0);
    gather_k<<<GATHER_BLOCKS, 256, 0, stream>>>(hb, dis, fc, ell, b1, agg, stats);
    bnfix_k<<<1, 128, 0, stream>>>(stats, g1, be1, scb, shb);

    // Layer 2
    mgemm_k<<<GB, 256, 0, stream>>>(nullptr, agg, wt + 2 * 16384, scb, shb, dis, hb, 1);
    gather_k<<<GATHER_BLOCKS, 256, 0, stream>>>(hb, dis, fc, ell, b2, agg, stats + 256);
    bnfix_k<<<1, 128, 0, stream>>>(stats + 256, g2, be2, scb + 128, shb + 128);

    // Layer 3
    mgemm_k<<<GB, 256, 0, stream>>>(nullptr, agg, wt + 4 * 16384, scb + 128, shb + 128, dis, hb, 1);
    gather_k<<<GATHER_BLOCKS, 256, 0, stream>>>(hb, dis, fc, ell, b3, agg, stats + 512);
    bnfix_k<<<1, 128, 0, stream>>>(stats + 512, g3, be3, scb + 256, shb + 256);

    // Pool + head
    pool_k<<<512, 256, 0, stream>>>(agg, batch, scb + 256, shb + 256, p);
    head_k<<<NG, 128, 0, stream>>>(p, Wm1, bm1, Wm2, bm2, out);
}

// Round 10
// 354.844 us; speedup vs baseline: 1.6437x; 1.6437x over previous
//
#include <hip/hip_runtime.h>

#define NN 50000
#define NE 800000
#define DD 128
#define NG 250
#define BN_EPS 1e-5f
#define ELLW 64
#define GATHER_BLOCKS 2048
#define NSLOT 32

typedef unsigned short u16;
typedef __attribute__((ext_vector_type(8))) short bf16x8;
typedef __attribute__((ext_vector_type(4))) float f32x4;

__device__ inline u16 f2bf(float f) {
    union { float f; unsigned u; } c;
    c.f = f;
    unsigned r = c.u + 0x7fffu + ((c.u >> 16) & 1u);  // RTNE
    return (u16)(r >> 16);
}
__device__ inline float bf2f(u16 h) {
    union { unsigned u; float f; } c;
    c.u = (unsigned)h << 16;
    return c.f;
}
__device__ inline unsigned pack2bf(float lo, float hi) {
    return (unsigned)f2bf(lo) | ((unsigned)f2bf(hi) << 16);
}
__device__ inline float bf_lo(unsigned u) {
    union { unsigned u; float f; } c;
    c.u = u << 16;
    return c.f;
}
__device__ inline float bf_hi(unsigned u) {
    union { unsigned u; float f; } c;
    c.u = u & 0xffff0000u;
    return c.f;
}

// ---------------- ELL build ----------------

__global__ void fillell_k(const int* __restrict__ src, const int* __restrict__ dst,
                          int* __restrict__ fc, u16* __restrict__ ell) {
    int e = blockIdx.x * 256 + threadIdx.x;
    if (e < NE) {
        int d = dst[e];
        int pos = atomicAdd(&fc[d], 1);
        if (pos < ELLW) ell[(size_t)d * ELLW + pos] = (u16)src[e];
    }
}

__global__ void dis_k(const int* __restrict__ fc, float* __restrict__ dis) {
    int i = blockIdx.x * 256 + threadIdx.x;
    if (i < NN) dis[i] = 1.0f / sqrtf((float)(fc[i] + 1));
}

// ---------------- W prep: W(fp32 [k][n]) -> WhiT,WloT (bf16 [n][k]) ----------------

__global__ void wprep_k(const float* __restrict__ W1, const float* __restrict__ W2,
                        const float* __restrict__ W3, u16* __restrict__ wt) {
    int lid = blockIdx.x >> 6;                       // layer 0..2
    int idx = (blockIdx.x & 63) * 256 + threadIdx.x; // 0..16383
    const float* W = lid == 0 ? W1 : (lid == 1 ? W2 : W3);
    int k = idx >> 7, n = idx & 127;
    float w = W[idx];
    u16 hi = f2bf(w);
    u16 lo = f2bf(w - bf2f(hi));
    wt[((size_t)lid * 2 + 0) * 16384 + (size_t)n * 128 + k] = hi;
    wt[((size_t)lid * 2 + 1) * 16384 + (size_t)n * 128 + k] = lo;
}

// ---------------- MFMA GEMM: HB(bf16) = dis[row] * (act(A) @ (Whi+Wlo)) ----------------

__global__ __launch_bounds__(256) void mgemm_k(const float* __restrict__ A32,
                                               const u16* __restrict__ A16,
                                               const u16* __restrict__ WT,  // [2][128][128]
                                               const float* __restrict__ sc,
                                               const float* __restrict__ sh,
                                               const float* __restrict__ dis,
                                               u16* __restrict__ HB, int use_bn) {
    __shared__ u16 WL[2 * 128 * 128];   // 64KB
    __shared__ float scs[128], shs[128];
    int tid = threadIdx.x;
    if (use_bn && tid < 128) { scs[tid] = sc[tid]; shs[tid] = sh[tid]; }
    {
        const uint4* wg = (const uint4*)WT;
#pragma unroll
        for (int i = 0; i < 16; i++) {
            int ci = tid + i * 256;                  // 4096 chunks of 16B
            unsigned byte = (unsigned)ci * 16;
            unsigned n = (byte >> 8) & 127;
            unsigned swz = byte ^ ((n & 7) << 4);
            *(uint4*)((char*)WL + swz) = wg[ci];
        }
    }
    __syncthreads();

    int w = tid >> 6, lane = tid & 63;
    int col = lane & 15, lg = lane >> 4;
    int rowA = blockIdx.x * 64 + w * 16 + col;

    union { uint4 q; bf16x8 v; } afr[4];
#pragma unroll
    for (int s = 0; s < 4; s++) afr[s].q = make_uint4(0, 0, 0, 0);
    if (rowA < NN) {
        if (!use_bn) {  // layer 1: fp32 input, convert inline
            const float4* ap = (const float4*)(A32 + (size_t)rowA * DD);
#pragma unroll
            for (int s = 0; s < 4; s++) {
                float4 f0 = ap[s * 8 + lg * 2];
                float4 f1 = ap[s * 8 + lg * 2 + 1];
                afr[s].q = make_uint4(pack2bf(f0.x, f0.y), pack2bf(f0.z, f0.w),
                                      pack2bf(f1.x, f1.y), pack2bf(f1.z, f1.w));
            }
        } else {
            const uint4* ap = (const uint4*)(A16 + (size_t)rowA * DD);
#pragma unroll
            for (int s = 0; s < 4; s++) {
                uint4 q = ap[s * 4 + lg];
                unsigned uu[4] = {q.x, q.y, q.z, q.w};
                int cbase = s * 32 + lg * 8;
#pragma unroll
                for (int t = 0; t < 4; t++) {
                    int c0 = cbase + t * 2;
                    float f0 = fmaxf(fmaf(bf_lo(uu[t]), scs[c0], shs[c0]), 0.f);
                    float f1 = fmaxf(fmaf(bf_hi(uu[t]), scs[c0 + 1], shs[c0 + 1]), 0.f);
                    uu[t] = pack2bf(f0, f1);
                }
                afr[s].q = make_uint4(uu[0], uu[1], uu[2], uu[3]);
            }
        }
    }

    f32x4 acc[8];
#pragma unroll
    for (int cf = 0; cf < 8; cf++) { acc[cf][0] = 0.f; acc[cf][1] = 0.f; acc[cf][2] = 0.f; acc[cf][3] = 0.f; }

#pragma unroll
    for (int half = 0; half < 2; half++) {
#pragma unroll
        for (int s = 0; s < 4; s++) {
#pragma unroll
            for (int cf = 0; cf < 8; cf++) {
                int nn = cf * 16 + col;
                unsigned byte = (unsigned)half * 32768 + (unsigned)nn * 256
                              + (unsigned)(s * 64 + lg * 16);
                byte ^= ((nn & 7) << 4);
                bf16x8 b = *(const bf16x8*)((const char*)WL + byte);
                acc[cf] = __builtin_amdgcn_mfma_f32_16x16x32_bf16(afr[s].v, b, acc[cf], 0, 0, 0);
            }
        }
    }

#pragma unroll
    for (int r = 0; r < 4; r++) {
        int ro = blockIdx.x * 64 + w * 16 + lg * 4 + r;
        if (ro < NN) {
            float dv = dis[ro];
#pragma unroll
            for (int cf = 0; cf < 8; cf++) {
                HB[(size_t)ro * DD + cf * 16 + col] = f2bf(acc[cf][r] * dv);
            }
        }
    }
}

// ---------------- Gather (ELL) + self-loop + bias + BN stats (32 partial slots) ----------------

__global__ __launch_bounds__(256) void gather_k(const u16* __restrict__ HB,
                                                const float* __restrict__ dis,
                                                const int* __restrict__ fc,
                                                const u16* __restrict__ ell,
                                                const float* __restrict__ bias,
                                                u16* __restrict__ AGG,
                                                float* __restrict__ statsP) {
    __shared__ float s_sum[128], s_sq[128];
    int tid = threadIdx.x;
    if (tid < 128) { s_sum[tid] = 0.f; s_sq[tid] = 0.f; }
    __syncthreads();
    int lane = tid & 63;
    int wid = blockIdx.x * 4 + (tid >> 6);
    const int nwaves = GATHER_BLOCKS * 4;
    int c = lane * 2;
    float b0 = bias[c], b1 = bias[c + 1];
    float lsum0 = 0.f, lsum1 = 0.f, lsq0 = 0.f, lsq1 = 0.f;
    for (int v = wid; v < NN; v += nwaves) {
        int cntv = fc[v];
        if (cntv > ELLW) cntv = ELLW;
        int myidx = (lane < cntv) ? (int)ell[(size_t)v * ELLW + lane] : 0;
        float a0 = 0.f, a1 = 0.f;
        int j = 0;
        for (; j + 8 <= cntv; j += 8) {
            unsigned r[8];
#pragma unroll
            for (int q = 0; q < 8; q++) {
                int s = __shfl(myidx, j + q);
                r[q] = *(const unsigned*)(HB + (size_t)s * DD + c);
            }
#pragma unroll
            for (int q = 0; q < 8; q++) { a0 += bf_lo(r[q]); a1 += bf_hi(r[q]); }
        }
        for (; j < cntv; j++) {
            int s = __shfl(myidx, j);
            unsigned r0 = *(const unsigned*)(HB + (size_t)s * DD + c);
            a0 += bf_lo(r0);
            a1 += bf_hi(r0);
        }
        unsigned rsf = *(const unsigned*)(HB + (size_t)v * DD + c);
        float dv = dis[v];
        float o0 = fmaf(a0 + bf_lo(rsf), dv, b0);
        float o1 = fmaf(a1 + bf_hi(rsf), dv, b1);
        *(unsigned*)(AGG + (size_t)v * DD + c) = pack2bf(o0, o1);
        lsum0 += o0; lsum1 += o1;
        lsq0 += o0 * o0; lsq1 += o1 * o1;
    }
    atomicAdd(&s_sum[c], lsum0);
    atomicAdd(&s_sum[c + 1], lsum1);
    atomicAdd(&s_sq[c], lsq0);
    atomicAdd(&s_sq[c + 1], lsq1);
    __syncthreads();
    if (tid < 128) {
        float* slot = statsP + (size_t)(blockIdx.x & (NSLOT - 1)) * 256;
        atomicAdd(&slot[tid], s_sum[tid]);
        atomicAdd(&slot[128 + tid], s_sq[tid]);
    }
}

// ---------------- BN stats (reduce 32 slots) -> scale/shift ----------------

__global__ void bnfix_k(const float* __restrict__ statsP, const float* __restrict__ g,
                        const float* __restrict__ be, float* __restrict__ sc,
                        float* __restrict__ sh) {
    int c = threadIdx.x;
    float sum = 0.f, sq = 0.f;
#pragma unroll
    for (int s = 0; s < NSLOT; s++) {
        sum += statsP[(size_t)s * 256 + c];
        sq  += statsP[(size_t)s * 256 + 128 + c];
    }
    float mean = sum * (1.0f / NN);
    float var = sq * (1.0f / NN) - mean * mean;
    float scl = g[c] / sqrtf(var + BN_EPS);
    sc[c] = scl;
    sh[c] = be[c] - mean * scl;
}

// ---------------- Pool (bf16 agg) ----------------

__global__ __launch_bounds__(256) void pool_k(const u16* __restrict__ AGG,
                                              const int* __restrict__ batch,
                                              const float* __restrict__ sc,
                                              const float* __restrict__ sh,
                                              float* __restrict__ P) {
    int lane = threadIdx.x & 63;
    int wid = blockIdx.x * 4 + (threadIdx.x >> 6);
    int nw = gridDim.x * 4;
    int c = lane * 2;
    float sc0 = sc[c], sc1 = sc[c + 1], sh0 = sh[c], sh1 = sh[c + 1];
    int chunk = (NN + nw - 1) / nw;
    int v0 = wid * chunk, v1 = v0 + chunk;
    if (v1 > NN) v1 = NN;
    if (v0 >= NN) return;
    int curb = batch[v0];
    float acc0 = 0.f, acc1 = 0.f;
    for (int v = v0; v < v1; v++) {
        int b = batch[v];
        if (b != curb) {
            atomicAdd(&P[curb * 128 + c], acc0);
            atomicAdd(&P[curb * 128 + c + 1], acc1);
            acc0 = 0.f; acc1 = 0.f; curb = b;
        }
        unsigned hv = *(const unsigned*)(AGG + (size_t)v * DD + c);
        acc0 += fmaxf(fmaf(bf_lo(hv), sc0, sh0), 0.f);
        acc1 += fmaxf(fmaf(bf_hi(hv), sc1, sh1), 0.f);
    }
    atomicAdd(&P[curb * 128 + c], acc0);
    atomicAdd(&P[curb * 128 + c + 1], acc1);
}

// ---------------- Head ----------------

__global__ __launch_bounds__(128) void head_k(const float* __restrict__ P,
                                              const float* __restrict__ Wm1,
                                              const float* __restrict__ bm1,
                                              const float* __restrict__ Wm2,
                                              const float* __restrict__ bm2,
                                              float* __restrict__ OUT) {
    __shared__ float prow[128];
    __shared__ float red[128];
    int g = blockIdx.x, t = threadIdx.x;
    prow[t] = P[g * 128 + t];
    __syncthreads();
    float acc = bm1[t];
#pragma unroll 8
    for (int i = 0; i < 128; i++) acc = fmaf(prow[i], Wm1[i * 128 + t], acc);
    red[t] = fmaxf(acc, 0.f) * Wm2[t];
    __syncthreads();
    for (int off = 64; off > 0; off >>= 1) {
        if (t < off) red[t] += red[t + off];
        __syncthreads();
    }
    if (t == 0) OUT[g] = red[0] + bm2[0];
}

// ---------------- Launch ----------------

extern "C" void kernel_launch(void* const* d_in, const int* in_sizes, int n_in,
                              void* d_out, int out_size, void* d_ws, size_t ws_size,
                              hipStream_t stream) {
    const float* x   = (const float*)d_in[0];
    const int*  ei   = (const int*)d_in[1];
    const int*  batch= (const int*)d_in[2];
    const float* W1  = (const float*)d_in[3];
    const float* b1  = (const float*)d_in[4];
    const float* g1  = (const float*)d_in[5];
    const float* be1 = (const float*)d_in[6];
    const float* W2  = (const float*)d_in[7];
    const float* b2  = (const float*)d_in[8];
    const float* g2  = (const float*)d_in[9];
    const float* be2 = (const float*)d_in[10];
    const float* W3  = (const float*)d_in[11];
    const float* b3  = (const float*)d_in[12];
    const float* g3  = (const float*)d_in[13];
    const float* be3 = (const float*)d_in[14];
    const float* Wm1 = (const float*)d_in[15];
    const float* bm1 = (const float*)d_in[16];
    const float* Wm2 = (const float*)d_in[17];
    const float* bm2 = (const float*)d_in[18];
    float* out = (float*)d_out;

    char* ws = (char*)d_ws;
    size_t off = 0;
    auto alloc = [&](size_t bytes) -> void* {
        void* p = ws + off;
        off = (off + bytes + 255) & ~(size_t)255;
        return p;
    };
    int*   fc    = (int*)alloc((size_t)NN * 4);
    float* dis   = (float*)alloc((size_t)NN * 4);
    u16*   ell   = (u16*)alloc((size_t)NN * ELLW * 2);
    u16*   hb    = (u16*)alloc((size_t)NN * DD * 2);
    u16*   agg   = (u16*)alloc((size_t)NN * DD * 2);
    u16*   wt    = (u16*)alloc((size_t)3 * 2 * 16384 * 2);
    float* statsP= (float*)alloc((size_t)3 * NSLOT * 256 * 4);
    float* scb   = (float*)alloc(3 * 128 * 4);
    float* shb   = (float*)alloc(3 * 128 * 4);
    float* p     = (float*)alloc((size_t)NG * DD * 4);

    const int* srcI = ei;
    const int* dstI = ei + NE;

    hipMemsetAsync(fc, 0, (size_t)NN * 4, stream);
    hipMemsetAsync(statsP, 0, (size_t)3 * NSLOT * 256 * 4, stream);
    hipMemsetAsync(p, 0, (size_t)NG * DD * 4, stream);

    fillell_k<<<(NE + 255) / 256, 256, 0, stream>>>(srcI, dstI, fc, ell);
    dis_k<<<(NN + 255) / 256, 256, 0, stream>>>(fc, dis);
    wprep_k<<<192, 256, 0, stream>>>(W1, W2, W3, wt);

    const int GB = (NN + 63) / 64;
    const size_t SL = (size_t)NSLOT * 256;

    // Layer 1 (fp32 input converted inline)
    mgemm_k<<<GB, 256, 0, stream>>>(x, nullptr, wt, nullptr, nullptr, dis, hb, 0);
    gather_k<<<GATHER_BLOCKS, 256, 0, stream>>>(hb, dis, fc, ell, b1, agg, statsP);
    bnfix_k<<<1, 128, 0, stream>>>(statsP, g1, be1, scb, shb);

    // Layer 2
    mgemm_k<<<GB, 256, 0, stream>>>(nullptr, agg, wt + 2 * 16384, scb, shb, dis, hb, 1);
    gather_k<<<GATHER_BLOCKS, 256, 0, stream>>>(hb, dis, fc, ell, b2, agg, statsP + SL);
    bnfix_k<<<1, 128, 0, stream>>>(statsP + SL, g2, be2, scb + 128, shb + 128);

    // Layer 3
    mgemm_k<<<GB, 256, 0, stream>>>(nullptr, agg, wt + 4 * 16384, scb + 128, shb + 128, dis, hb, 1);
    gather_k<<<GATHER_BLOCKS, 256, 0, stream>>>(hb, dis, fc, ell, b3, agg, statsP + 2 * SL);
    bnfix_k<<<1, 128, 0, stream>>>(statsP + 2 * SL, g3, be3, scb + 256, shb + 256);

    // Pool + head
    pool_k<<<512, 256, 0, stream>>>(agg, batch, scb + 256, shb + 256, p);
    head_k<<<NG, 128, 0, stream>>>(p, Wm1, bm1, Wm2, bm2, out);
}

// Round 11
// 333.499 us; speedup vs baseline: 1.7489x; 1.0640x over previous
//
#include <hip/hip_runtime.h>

#define NN 50000
#define NE 800000
#define DD 128
#define NG 250
#define BN_EPS 1e-5f
#define ELLW 64
#define GATHER_BLOCKS 2048
#define NSLOT 128

#define NBK 256          // dst-range buckets
#define BKRANGE 196      // nodes per bucket (256*196 >= 50000)
#define BKCAP 4608       // entries per bucket (mean 3136, ~26 sigma)
#define P1_BLOCKS 250
#define P1_CHUNK 3200    // 250*3200 = 800000

typedef unsigned short u16;
typedef __attribute__((ext_vector_type(8))) short bf16x8;
typedef __attribute__((ext_vector_type(4))) float f32x4;

__device__ inline u16 f2bf(float f) {
    union { float f; unsigned u; } c;
    c.f = f;
    unsigned r = c.u + 0x7fffu + ((c.u >> 16) & 1u);  // RTNE
    return (u16)(r >> 16);
}
__device__ inline float bf2f(u16 h) {
    union { unsigned u; float f; } c;
    c.u = (unsigned)h << 16;
    return c.f;
}
__device__ inline unsigned pack2bf(float lo, float hi) {
    return (unsigned)f2bf(lo) | ((unsigned)f2bf(hi) << 16);
}
__device__ inline float bf_lo(unsigned u) {
    union { unsigned u; float f; } c;
    c.u = u << 16;
    return c.f;
}
__device__ inline float bf_hi(unsigned u) {
    union { unsigned u; float f; } c;
    c.u = u & 0xffff0000u;
    return c.f;
}

// ---------------- ELL build, pass 1: LDS-staged binning into dst-range buckets ----------------

__global__ __launch_bounds__(256) void binpass_k(const int* __restrict__ src,
                                                 const int* __restrict__ dst,
                                                 int* __restrict__ bcnt,
                                                 unsigned* __restrict__ buckets) {
    __shared__ unsigned bins[NBK][64];   // 64 KB
    __shared__ int bn[NBK];
    __shared__ int bbase[NBK];
    int tid = threadIdx.x;
    for (int i = tid; i < NBK; i += 256) bn[i] = 0;
    __syncthreads();
    int e0 = blockIdx.x * P1_CHUNK;
    for (int i = tid; i < P1_CHUNK; i += 256) {
        int e = e0 + i;
        if (e < NE) {
            int d = dst[e];
            int s = src[e];
            int bk = d / BKRANGE;
            int dl = d - bk * BKRANGE;
            unsigned ent = ((unsigned)dl << 16) | (unsigned)s;
            int pos = atomicAdd(&bn[bk], 1);
            if (pos < 64) {
                bins[bk][pos] = ent;
            } else {  // overflow slow path (statistically never)
                int gb = atomicAdd(&bcnt[bk], 1);
                if (gb < BKCAP) buckets[(size_t)bk * BKCAP + gb] = ent;
            }
        }
    }
    __syncthreads();
    if (tid < NBK) {
        int cnt = bn[tid]; if (cnt > 64) cnt = 64;
        bbase[tid] = cnt ? atomicAdd(&bcnt[tid], cnt) : 0;
    }
    __syncthreads();
    if (tid < NBK) {
        int cnt = bn[tid]; if (cnt > 64) cnt = 64;
        int base = bbase[tid];
        unsigned* gb = buckets + (size_t)tid * BKCAP;
        for (int i = 0; i < cnt; i++) {
            int g = base + i;
            if (g < BKCAP) gb[g] = bins[tid][i];
        }
    }
}

// ---------------- ELL build, pass 2: bucket -> LDS ELL slice -> coalesced flush ----------------

__global__ __launch_bounds__(256) void ellpass_k(const int* __restrict__ bcnt,
                                                 const unsigned* __restrict__ buckets,
                                                 int* __restrict__ fc,
                                                 float* __restrict__ dis,
                                                 u16* __restrict__ ell) {
    __shared__ u16 lell[BKRANGE * ELLW];   // 25088 B
    __shared__ int lcnt[BKRANGE];
    int b = blockIdx.x, tid = threadIdx.x;
    for (int i = tid; i < BKRANGE; i += 256) lcnt[i] = 0;
    __syncthreads();
    int cnt = bcnt[b]; if (cnt > BKCAP) cnt = BKCAP;
    const unsigned* bk = buckets + (size_t)b * BKCAP;
    for (int i = tid; i < cnt; i += 256) {
        unsigned ent = bk[i];
        int dl = ent >> 16;
        int pos = atomicAdd(&lcnt[dl], 1);
        if (pos < ELLW) lell[dl * ELLW + pos] = (u16)(ent & 0xffffu);
    }
    __syncthreads();
    int n0 = b * BKRANGE;
    int nrows = NN - n0; if (nrows > BKRANGE) nrows = BKRANGE; if (nrows < 0) nrows = 0;
    int words = nrows * (ELLW / 2);
    unsigned* gell = (unsigned*)(ell + (size_t)n0 * ELLW);
    const unsigned* l32 = (const unsigned*)lell;
    for (int i = tid; i < words; i += 256) gell[i] = l32[i];
    for (int i = tid; i < nrows; i += 256) {
        int c = lcnt[i]; if (c > ELLW) c = ELLW;
        fc[n0 + i] = c;
        dis[n0 + i] = 1.0f / sqrtf((float)(c + 1));
    }
}

// ---------------- W prep: W(fp32 [k][n]) -> WhiT,WloT (bf16 [n][k]) ----------------

__global__ void wprep_k(const float* __restrict__ W1, const float* __restrict__ W2,
                        const float* __restrict__ W3, u16* __restrict__ wt) {
    int lid = blockIdx.x >> 6;                       // layer 0..2
    int idx = (blockIdx.x & 63) * 256 + threadIdx.x; // 0..16383
    const float* W = lid == 0 ? W1 : (lid == 1 ? W2 : W3);
    int k = idx >> 7, n = idx & 127;
    float w = W[idx];
    u16 hi = f2bf(w);
    u16 lo = f2bf(w - bf2f(hi));
    wt[((size_t)lid * 2 + 0) * 16384 + (size_t)n * 128 + k] = hi;
    wt[((size_t)lid * 2 + 1) * 16384 + (size_t)n * 128 + k] = lo;
}

// ---------------- MFMA GEMM: HB(bf16) = dis[row] * (act(A) @ (Whi+Wlo)) ----------------

__global__ __launch_bounds__(256) void mgemm_k(const float* __restrict__ A32,
                                               const u16* __restrict__ A16,
                                               const u16* __restrict__ WT,  // [2][128][128]
                                               const float* __restrict__ sc,
                                               const float* __restrict__ sh,
                                               const float* __restrict__ dis,
                                               u16* __restrict__ HB, int use_bn) {
    __shared__ u16 WL[2 * 128 * 128];   // 64KB
    __shared__ float scs[128], shs[128];
    int tid = threadIdx.x;
    if (use_bn && tid < 128) { scs[tid] = sc[tid]; shs[tid] = sh[tid]; }
    {
        const uint4* wg = (const uint4*)WT;
#pragma unroll
        for (int i = 0; i < 16; i++) {
            int ci = tid + i * 256;
            unsigned byte = (unsigned)ci * 16;
            unsigned n = (byte >> 8) & 127;
            unsigned swz = byte ^ ((n & 7) << 4);
            *(uint4*)((char*)WL + swz) = wg[ci];
        }
    }
    __syncthreads();

    int w = tid >> 6, lane = tid & 63;
    int col = lane & 15, lg = lane >> 4;
    int rowA = blockIdx.x * 64 + w * 16 + col;

    union { uint4 q; bf16x8 v; } afr[4];
#pragma unroll
    for (int s = 0; s < 4; s++) afr[s].q = make_uint4(0, 0, 0, 0);
    if (rowA < NN) {
        if (!use_bn) {
            const float4* ap = (const float4*)(A32 + (size_t)rowA * DD);
#pragma unroll
            for (int s = 0; s < 4; s++) {
                float4 f0 = ap[s * 8 + lg * 2];
                float4 f1 = ap[s * 8 + lg * 2 + 1];
                afr[s].q = make_uint4(pack2bf(f0.x, f0.y), pack2bf(f0.z, f0.w),
                                      pack2bf(f1.x, f1.y), pack2bf(f1.z, f1.w));
            }
        } else {
            const uint4* ap = (const uint4*)(A16 + (size_t)rowA * DD);
#pragma unroll
            for (int s = 0; s < 4; s++) {
                uint4 q = ap[s * 4 + lg];
                unsigned uu[4] = {q.x, q.y, q.z, q.w};
                int cbase = s * 32 + lg * 8;
#pragma unroll
                for (int t = 0; t < 4; t++) {
                    int c0 = cbase + t * 2;
                    float f0 = fmaxf(fmaf(bf_lo(uu[t]), scs[c0], shs[c0]), 0.f);
                    float f1 = fmaxf(fmaf(bf_hi(uu[t]), scs[c0 + 1], shs[c0 + 1]), 0.f);
                    uu[t] = pack2bf(f0, f1);
                }
                afr[s].q = make_uint4(uu[0], uu[1], uu[2], uu[3]);
            }
        }
    }

    f32x4 acc[8];
#pragma unroll
    for (int cf = 0; cf < 8; cf++) { acc[cf][0] = 0.f; acc[cf][1] = 0.f; acc[cf][2] = 0.f; acc[cf][3] = 0.f; }

#pragma unroll
    for (int half = 0; half < 2; half++) {
#pragma unroll
        for (int s = 0; s < 4; s++) {
#pragma unroll
            for (int cf = 0; cf < 8; cf++) {
                int nn = cf * 16 + col;
                unsigned byte = (unsigned)half * 32768 + (unsigned)nn * 256
                              + (unsigned)(s * 64 + lg * 16);
                byte ^= ((nn & 7) << 4);
                bf16x8 b = *(const bf16x8*)((const char*)WL + byte);
                acc[cf] = __builtin_amdgcn_mfma_f32_16x16x32_bf16(afr[s].v, b, acc[cf], 0, 0, 0);
            }
        }
    }

#pragma unroll
    for (int r = 0; r < 4; r++) {
        int ro = blockIdx.x * 64 + w * 16 + lg * 4 + r;
        if (ro < NN) {
            float dv = dis[ro];
#pragma unroll
            for (int cf = 0; cf < 8; cf++) {
                HB[(size_t)ro * DD + cf * 16 + col] = f2bf(acc[cf][r] * dv);
            }
        }
    }
}

// ---------------- Gather (ELL) + self-loop + bias + BN stats (128 partial slots) ----------------

__global__ __launch_bounds__(256) void gather_k(const u16* __restrict__ HB,
                                                const float* __restrict__ dis,
                                                const int* __restrict__ fc,
                                                const u16* __restrict__ ell,
                                                const float* __restrict__ bias,
                                                u16* __restrict__ AGG,
                                                float* __restrict__ statsP) {
    __shared__ float s_sum[128], s_sq[128];
    int tid = threadIdx.x;
    if (tid < 128) { s_sum[tid] = 0.f; s_sq[tid] = 0.f; }
    __syncthreads();
    int lane = tid & 63;
    int wid = blockIdx.x * 4 + (tid >> 6);
    const int nwaves = GATHER_BLOCKS * 4;
    int c = lane * 2;
    float b0 = bias[c], b1 = bias[c + 1];
    float lsum0 = 0.f, lsum1 = 0.f, lsq0 = 0.f, lsq1 = 0.f;
    for (int v = wid; v < NN; v += nwaves) {
        int cntv = fc[v];
        if (cntv > ELLW) cntv = ELLW;
        int myidx = (lane < cntv) ? (int)ell[(size_t)v * ELLW + lane] : 0;
        float a0 = 0.f, a1 = 0.f;
        int j = 0;
        for (; j + 8 <= cntv; j += 8) {
            unsigned r[8];
#pragma unroll
            for (int q = 0; q < 8; q++) {
                int s = __shfl(myidx, j + q);
                r[q] = *(const unsigned*)(HB + (size_t)s * DD + c);
            }
#pragma unroll
            for (int q = 0; q < 8; q++) { a0 += bf_lo(r[q]); a1 += bf_hi(r[q]); }
        }
        for (; j < cntv; j++) {
            int s = __shfl(myidx, j);
            unsigned r0 = *(const unsigned*)(HB + (size_t)s * DD + c);
            a0 += bf_lo(r0);
            a1 += bf_hi(r0);
        }
        unsigned rsf = *(const unsigned*)(HB + (size_t)v * DD + c);
        float dv = dis[v];
        float o0 = fmaf(a0 + bf_lo(rsf), dv, b0);
        float o1 = fmaf(a1 + bf_hi(rsf), dv, b1);
        *(unsigned*)(AGG + (size_t)v * DD + c) = pack2bf(o0, o1);
        lsum0 += o0; lsum1 += o1;
        lsq0 += o0 * o0; lsq1 += o1 * o1;
    }
    atomicAdd(&s_sum[c], lsum0);
    atomicAdd(&s_sum[c + 1], lsum1);
    atomicAdd(&s_sq[c], lsq0);
    atomicAdd(&s_sq[c + 1], lsq1);
    __syncthreads();
    if (tid < 128) {
        float* slot = statsP + (size_t)(blockIdx.x & (NSLOT - 1)) * 256;
        atomicAdd(&slot[tid], s_sum[tid]);
        atomicAdd(&slot[128 + tid], s_sq[tid]);
    }
}

// ---------------- BN stats (reduce slots) -> scale/shift ----------------

__global__ void bnfix_k(const float* __restrict__ statsP, const float* __restrict__ g,
                        const float* __restrict__ be, float* __restrict__ sc,
                        float* __restrict__ sh) {
    int c = threadIdx.x;
    float sum = 0.f, sq = 0.f;
    for (int s = 0; s < NSLOT; s++) {
        sum += statsP[(size_t)s * 256 + c];
        sq  += statsP[(size_t)s * 256 + 128 + c];
    }
    float mean = sum * (1.0f / NN);
    float var = sq * (1.0f / NN) - mean * mean;
    float scl = g[c] / sqrtf(var + BN_EPS);
    sc[c] = scl;
    sh[c] = be[c] - mean * scl;
}

// ---------------- Pool (bf16 agg) ----------------

__global__ __launch_bounds__(256) void pool_k(const u16* __restrict__ AGG,
                                              const int* __restrict__ batch,
                                              const float* __restrict__ sc,
                                              const float* __restrict__ sh,
                                              float* __restrict__ P) {
    int lane = threadIdx.x & 63;
    int wid = blockIdx.x * 4 + (threadIdx.x >> 6);
    int nw = gridDim.x * 4;
    int c = lane * 2;
    float sc0 = sc[c], sc1 = sc[c + 1], sh0 = sh[c], sh1 = sh[c + 1];
    int chunk = (NN + nw - 1) / nw;
    int v0 = wid * chunk, v1 = v0 + chunk;
    if (v1 > NN) v1 = NN;
    if (v0 >= NN) return;
    int curb = batch[v0];
    float acc0 = 0.f, acc1 = 0.f;
    for (int v = v0; v < v1; v++) {
        int b = batch[v];
        if (b != curb) {
            atomicAdd(&P[curb * 128 + c], acc0);
            atomicAdd(&P[curb * 128 + c + 1], acc1);
            acc0 = 0.f; acc1 = 0.f; curb = b;
        }
        unsigned hv = *(const unsigned*)(AGG + (size_t)v * DD + c);
        acc0 += fmaxf(fmaf(bf_lo(hv), sc0, sh0), 0.f);
        acc1 += fmaxf(fmaf(bf_hi(hv), sc1, sh1), 0.f);
    }
    atomicAdd(&P[curb * 128 + c], acc0);
    atomicAdd(&P[curb * 128 + c + 1], acc1);
}

// ---------------- Head ----------------

__global__ __launch_bounds__(128) void head_k(const float* __restrict__ P,
                                              const float* __restrict__ Wm1,
                                              const float* __restrict__ bm1,
                                              const float* __restrict__ Wm2,
                                              const float* __restrict__ bm2,
                                              float* __restrict__ OUT) {
    __shared__ float prow[128];
    __shared__ float red[128];
    int g = blockIdx.x, t = threadIdx.x;
    prow[t] = P[g * 128 + t];
    __syncthreads();
    float acc = bm1[t];
#pragma unroll 8
    for (int i = 0; i < 128; i++) acc = fmaf(prow[i], Wm1[i * 128 + t], acc);
    red[t] = fmaxf(acc, 0.f) * Wm2[t];
    __syncthreads();
    for (int off = 64; off > 0; off >>= 1) {
        if (t < off) red[t] += red[t + off];
        __syncthreads();
    }
    if (t == 0) OUT[g] = red[0] + bm2[0];
}

// ---------------- Launch ----------------

extern "C" void kernel_launch(void* const* d_in, const int* in_sizes, int n_in,
                              void* d_out, int out_size, void* d_ws, size_t ws_size,
                              hipStream_t stream) {
    const float* x   = (const float*)d_in[0];
    const int*  ei   = (const int*)d_in[1];
    const int*  batch= (const int*)d_in[2];
    const float* W1  = (const float*)d_in[3];
    const float* b1  = (const float*)d_in[4];
    const float* g1  = (const float*)d_in[5];
    const float* be1 = (const float*)d_in[6];
    const float* W2  = (const float*)d_in[7];
    const float* b2  = (const float*)d_in[8];
    const float* g2  = (const float*)d_in[9];
    const float* be2 = (const float*)d_in[10];
    const float* W3  = (const float*)d_in[11];
    const float* b3  = (const float*)d_in[12];
    const float* g3  = (const float*)d_in[13];
    const float* be3 = (const float*)d_in[14];
    const float* Wm1 = (const float*)d_in[15];
    const float* bm1 = (const float*)d_in[16];
    const float* Wm2 = (const float*)d_in[17];
    const float* bm2 = (const float*)d_in[18];
    float* out = (float*)d_out;

    char* ws = (char*)d_ws;
    size_t off = 0;
    auto alloc = [&](size_t bytes) -> void* {
        void* p = ws + off;
        off = (off + bytes + 255) & ~(size_t)255;
        return p;
    };
    int*   fc    = (int*)alloc((size_t)NN * 4);
    float* dis   = (float*)alloc((size_t)NN * 4);
    u16*   ell   = (u16*)alloc((size_t)NN * ELLW * 2);
    u16*   hb    = (u16*)alloc((size_t)NN * DD * 2);
    u16*   agg   = (u16*)alloc((size_t)NN * DD * 2);
    u16*   wt    = (u16*)alloc((size_t)3 * 2 * 16384 * 2);
    float* scb   = (float*)alloc(3 * 128 * 4);
    float* shb   = (float*)alloc(3 * 128 * 4);
    unsigned* buckets = (unsigned*)alloc((size_t)NBK * BKCAP * 4);
    // zero region: statsP (3*NSLOT*256*4 = 393216) + p (128000) + bcnt (1024), contiguous
    float* statsP= (float*)alloc((size_t)3 * NSLOT * 256 * 4);
    float* p     = (float*)alloc((size_t)NG * DD * 4);
    int*   bcnt  = (int*)alloc((size_t)NBK * 4);

    const int* srcI = ei;
    const int* dstI = ei + NE;

    hipMemsetAsync(statsP, 0, (size_t)3 * NSLOT * 256 * 4 + (size_t)NG * DD * 4 + (size_t)NBK * 4, stream);

    binpass_k<<<P1_BLOCKS, 256, 0, stream>>>(srcI, dstI, bcnt, buckets);
    ellpass_k<<<NBK, 256, 0, stream>>>(bcnt, buckets, fc, dis, ell);
    wprep_k<<<192, 256, 0, stream>>>(W1, W2, W3, wt);

    const int GB = (NN + 63) / 64;
    const size_t SL = (size_t)NSLOT * 256;

    // Layer 1 (fp32 input converted inline)
    mgemm_k<<<GB, 256, 0, stream>>>(x, nullptr, wt, nullptr, nullptr, dis, hb, 0);
    gather_k<<<GATHER_BLOCKS, 256, 0, stream>>>(hb, dis, fc, ell, b1, agg, statsP);
    bnfix_k<<<1, 128, 0, stream>>>(statsP, g1, be1, scb, shb);

    // Layer 2
    mgemm_k<<<GB, 256, 0, stream>>>(nullptr, agg, wt + 2 * 16384, scb, shb, dis, hb, 1);
    gather_k<<<GATHER_BLOCKS, 256, 0, stream>>>(hb, dis, fc, ell, b2, agg, statsP + SL);
    bnfix_k<<<1, 128, 0, stream>>>(statsP + SL, g2, be2, scb + 128, shb + 128);

    // Layer 3
    mgemm_k<<<GB, 256, 0, stream>>>(nullptr, agg, wt + 4 * 16384, scb + 128, shb + 128, dis, hb, 1);
    gather_k<<<GATHER_BLOCKS, 256, 0, stream>>>(hb, dis, fc, ell, b3, agg, statsP + 2 * SL);
    bnfix_k<<<1, 128, 0, stream>>>(statsP + 2 * SL, g3, be3, scb + 256, shb + 256);

    // Pool + head
    pool_k<<<512, 256, 0, stream>>>(agg, batch, scb + 256, shb + 256, p);
    head_k<<<NG, 128, 0, stream>>>(p, Wm1, bm1, Wm2, bm2, out);
}

// Round 12
// 313.406 us; speedup vs baseline: 1.8611x; 1.0641x over previous
//
#include <hip/hip_runtime.h>

#define NN 50000
#define NE 800000
#define DD 128
#define NG 250
#define BN_EPS 1e-5f
#define ELLW 64
#define GATHER_BLOCKS 2048
#define NSLOT 32

#define NBK 256          // dst-range buckets
#define BKRANGE 196      // nodes per bucket (256*196 >= 50000)
#define BKCAP 4608       // entries per bucket (mean 3136, ~26 sigma)
#define P1_BLOCKS 250
#define P1_CHUNK 3200    // 250*3200 = 800000

typedef unsigned short u16;
typedef __attribute__((ext_vector_type(8))) short bf16x8;
typedef __attribute__((ext_vector_type(4))) float f32x4;

__device__ inline u16 f2bf(float f) {
    union { float f; unsigned u; } c;
    c.f = f;
    unsigned r = c.u + 0x7fffu + ((c.u >> 16) & 1u);  // RTNE
    return (u16)(r >> 16);
}
__device__ inline float bf2f(u16 h) {
    union { unsigned u; float f; } c;
    c.u = (unsigned)h << 16;
    return c.f;
}
__device__ inline unsigned pack2bf(float lo, float hi) {
    return (unsigned)f2bf(lo) | ((unsigned)f2bf(hi) << 16);
}
__device__ inline float bf_lo(unsigned u) {
    union { unsigned u; float f; } c;
    c.u = u << 16;
    return c.f;
}
__device__ inline float bf_hi(unsigned u) {
    union { unsigned u; float f; } c;
    c.u = u & 0xffff0000u;
    return c.f;
}

// ---------------- ELL build, pass 1: LDS-staged binning into dst-range buckets ----------------

__global__ __launch_bounds__(256) void binpass_k(const int* __restrict__ src,
                                                 const int* __restrict__ dst,
                                                 int* __restrict__ bcnt,
                                                 unsigned* __restrict__ buckets) {
    __shared__ unsigned bins[NBK][64];   // 64 KB
    __shared__ int bn[NBK];
    __shared__ int bbase[NBK];
    int tid = threadIdx.x;
    for (int i = tid; i < NBK; i += 256) bn[i] = 0;
    __syncthreads();
    int e0 = blockIdx.x * P1_CHUNK;
    for (int i = tid; i < P1_CHUNK; i += 256) {
        int e = e0 + i;
        if (e < NE) {
            int d = dst[e];
            int s = src[e];
            int bk = d / BKRANGE;
            int dl = d - bk * BKRANGE;
            unsigned ent = ((unsigned)dl << 16) | (unsigned)s;
            int pos = atomicAdd(&bn[bk], 1);
            if (pos < 64) {
                bins[bk][pos] = ent;
            } else {  // overflow slow path (statistically never)
                int gb = atomicAdd(&bcnt[bk], 1);
                if (gb < BKCAP) buckets[(size_t)bk * BKCAP + gb] = ent;
            }
        }
    }
    __syncthreads();
    if (tid < NBK) {
        int cnt = bn[tid]; if (cnt > 64) cnt = 64;
        bbase[tid] = cnt ? atomicAdd(&bcnt[tid], cnt) : 0;
    }
    __syncthreads();
    if (tid < NBK) {
        int cnt = bn[tid]; if (cnt > 64) cnt = 64;
        int base = bbase[tid];
        unsigned* gb = buckets + (size_t)tid * BKCAP;
        for (int i = 0; i < cnt; i++) {
            int g = base + i;
            if (g < BKCAP) gb[g] = bins[tid][i];
        }
    }
}

// ---------------- ELL build, pass 2: bucket -> sentinel-padded LDS ELL -> coalesced flush ----------------
// fc stores roundup8(cnt); pad slots hold sentinel NN -> zero row of HB.

__global__ __launch_bounds__(256) void ellpass_k(const int* __restrict__ bcnt,
                                                 const unsigned* __restrict__ buckets,
                                                 int* __restrict__ fc,
                                                 float* __restrict__ dis,
                                                 u16* __restrict__ ell,
                                                 u16* __restrict__ hb) {
    __shared__ u16 lell[BKRANGE * ELLW];   // 25088 B
    __shared__ int lcnt[BKRANGE];
    int b = blockIdx.x, tid = threadIdx.x;
    for (int i = tid; i < BKRANGE; i += 256) lcnt[i] = 0;
    {   // init all slots to sentinel NN
        unsigned sent2 = ((unsigned)NN << 16) | (unsigned)NN;
        unsigned* l32 = (unsigned*)lell;
        for (int i = tid; i < BKRANGE * ELLW / 2; i += 256) l32[i] = sent2;
    }
    __syncthreads();
    int cnt = bcnt[b]; if (cnt > BKCAP) cnt = BKCAP;
    const unsigned* bk = buckets + (size_t)b * BKCAP;
    for (int i = tid; i < cnt; i += 256) {
        unsigned ent = bk[i];
        int dl = ent >> 16;
        int pos = atomicAdd(&lcnt[dl], 1);
        if (pos < ELLW) lell[dl * ELLW + pos] = (u16)(ent & 0xffffu);
    }
    __syncthreads();
    int n0 = b * BKRANGE;
    int nrows = NN - n0; if (nrows > BKRANGE) nrows = BKRANGE; if (nrows < 0) nrows = 0;
    int words = nrows * (ELLW / 2);
    unsigned* gell = (unsigned*)(ell + (size_t)n0 * ELLW);
    const unsigned* l32 = (const unsigned*)lell;
    for (int i = tid; i < words; i += 256) gell[i] = l32[i];
    for (int i = tid; i < nrows; i += 256) {
        int c = lcnt[i]; if (c > ELLW) c = ELLW;
        fc[n0 + i] = (c + 7) & ~7;   // padded count for gather
        dis[n0 + i] = 1.0f / sqrtf((float)(c + 1));
    }
    if (b == 0 && tid < 64) ((unsigned*)(hb + (size_t)NN * DD))[tid] = 0;  // zero row
}

// ---------------- W prep: W(fp32 [k][n]) -> WhiT,WloT (bf16 [n][k]) ----------------

__global__ void wprep_k(const float* __restrict__ W1, const float* __restrict__ W2,
                        const float* __restrict__ W3, u16* __restrict__ wt) {
    int lid = blockIdx.x >> 6;                       // layer 0..2
    int idx = (blockIdx.x & 63) * 256 + threadIdx.x; // 0..16383
    const float* W = lid == 0 ? W1 : (lid == 1 ? W2 : W3);
    int k = idx >> 7, n = idx & 127;
    float w = W[idx];
    u16 hi = f2bf(w);
    u16 lo = f2bf(w - bf2f(hi));
    wt[((size_t)lid * 2 + 0) * 16384 + (size_t)n * 128 + k] = hi;
    wt[((size_t)lid * 2 + 1) * 16384 + (size_t)n * 128 + k] = lo;
}

// ---------------- MFMA GEMM: HB(bf16) = dis[row] * (act(A) @ (Whi+Wlo)) ----------------
// BN sc/sh computed in-preamble from statsP partial slots (fused bnfix).

__global__ __launch_bounds__(256) void mgemm_k(const float* __restrict__ A32,
                                               const u16* __restrict__ A16,
                                               const u16* __restrict__ WT,  // [2][128][128]
                                               const float* __restrict__ statsP,
                                               const float* __restrict__ g,
                                               const float* __restrict__ be,
                                               const float* __restrict__ dis,
                                               u16* __restrict__ HB, int use_bn) {
    __shared__ u16 WL[2 * 128 * 128];   // 64KB
    __shared__ float scs[128], shs[128];
    int tid = threadIdx.x;
    if (use_bn && tid < 128) {
        float sum = 0.f, sq = 0.f;
#pragma unroll
        for (int s = 0; s < NSLOT; s++) {
            sum += statsP[(size_t)s * 256 + tid];
            sq  += statsP[(size_t)s * 256 + 128 + tid];
        }
        float mean = sum * (1.0f / NN);
        float var = sq * (1.0f / NN) - mean * mean;
        float scl = g[tid] / sqrtf(var + BN_EPS);
        scs[tid] = scl;
        shs[tid] = be[tid] - mean * scl;
    }
    {
        const uint4* wg = (const uint4*)WT;
#pragma unroll
        for (int i = 0; i < 16; i++) {
            int ci = tid + i * 256;
            unsigned byte = (unsigned)ci * 16;
            unsigned n = (byte >> 8) & 127;
            unsigned swz = byte ^ ((n & 7) << 4);
            *(uint4*)((char*)WL + swz) = wg[ci];
        }
    }
    __syncthreads();

    int w = tid >> 6, lane = tid & 63;
    int col = lane & 15, lg = lane >> 4;
    int rowA = blockIdx.x * 64 + w * 16 + col;

    union { uint4 q; bf16x8 v; } afr[4];
#pragma unroll
    for (int s = 0; s < 4; s++) afr[s].q = make_uint4(0, 0, 0, 0);
    if (rowA < NN) {
        if (!use_bn) {
            const float4* ap = (const float4*)(A32 + (size_t)rowA * DD);
#pragma unroll
            for (int s = 0; s < 4; s++) {
                float4 f0 = ap[s * 8 + lg * 2];
                float4 f1 = ap[s * 8 + lg * 2 + 1];
                afr[s].q = make_uint4(pack2bf(f0.x, f0.y), pack2bf(f0.z, f0.w),
                                      pack2bf(f1.x, f1.y), pack2bf(f1.z, f1.w));
            }
        } else {
            const uint4* ap = (const uint4*)(A16 + (size_t)rowA * DD);
#pragma unroll
            for (int s = 0; s < 4; s++) {
                uint4 q = ap[s * 4 + lg];
                unsigned uu[4] = {q.x, q.y, q.z, q.w};
                int cbase = s * 32 + lg * 8;
#pragma unroll
                for (int t = 0; t < 4; t++) {
                    int c0 = cbase + t * 2;
                    float f0 = fmaxf(fmaf(bf_lo(uu[t]), scs[c0], shs[c0]), 0.f);
                    float f1 = fmaxf(fmaf(bf_hi(uu[t]), scs[c0 + 1], shs[c0 + 1]), 0.f);
                    uu[t] = pack2bf(f0, f1);
                }
                afr[s].q = make_uint4(uu[0], uu[1], uu[2], uu[3]);
            }
        }
    }

    f32x4 acc[8];
#pragma unroll
    for (int cf = 0; cf < 8; cf++) { acc[cf][0] = 0.f; acc[cf][1] = 0.f; acc[cf][2] = 0.f; acc[cf][3] = 0.f; }

#pragma unroll
    for (int half = 0; half < 2; half++) {
#pragma unroll
        for (int s = 0; s < 4; s++) {
#pragma unroll
            for (int cf = 0; cf < 8; cf++) {
                int nn = cf * 16 + col;
                unsigned byte = (unsigned)half * 32768 + (unsigned)nn * 256
                              + (unsigned)(s * 64 + lg * 16);
                byte ^= ((nn & 7) << 4);
                bf16x8 b = *(const bf16x8*)((const char*)WL + byte);
                acc[cf] = __builtin_amdgcn_mfma_f32_16x16x32_bf16(afr[s].v, b, acc[cf], 0, 0, 0);
            }
        }
    }

#pragma unroll
    for (int r = 0; r < 4; r++) {
        int ro = blockIdx.x * 64 + w * 16 + lg * 4 + r;
        if (ro < NN) {
            float dv = dis[ro];
#pragma unroll
            for (int cf = 0; cf < 8; cf++) {
                HB[(size_t)ro * DD + cf * 16 + col] = f2bf(acc[cf][r] * dv);
            }
        }
    }
}

// ---------------- Gather (sentinel-padded ELL) + self-loop + bias + BN stats ----------------
// fc[v] is a multiple of 8; pad indices point at HB's zero row. No tail, no predicates.

__global__ __launch_bounds__(256) void gather_k(const u16* __restrict__ HB,
                                                const float* __restrict__ dis,
                                                const int* __restrict__ fc,
                                                const u16* __restrict__ ell,
                                                const float* __restrict__ bias,
                                                u16* __restrict__ AGG,
                                                float* __restrict__ statsP) {
    __shared__ float s_sum[128], s_sq[128];
    int tid = threadIdx.x;
    if (tid < 128) { s_sum[tid] = 0.f; s_sq[tid] = 0.f; }
    __syncthreads();
    int lane = tid & 63;
    int wid = blockIdx.x * 4 + (tid >> 6);
    const int nwaves = GATHER_BLOCKS * 4;
    int c = lane * 2;
    float b0 = bias[c], b1 = bias[c + 1];
    float lsum0 = 0.f, lsum1 = 0.f, lsq0 = 0.f, lsq1 = 0.f;
    for (int v = wid; v < NN; v += nwaves) {
        int cnt8 = fc[v];
        int myidx = (int)ell[(size_t)v * ELLW + lane];
        float a0 = 0.f, a1 = 0.f;
        for (int j = 0; j < cnt8; j += 8) {
            unsigned r[8];
#pragma unroll
            for (int q = 0; q < 8; q++) {
                int s = __shfl(myidx, j + q);
                r[q] = *(const unsigned*)(HB + (size_t)s * DD + c);
            }
#pragma unroll
            for (int q = 0; q < 8; q++) { a0 += bf_lo(r[q]); a1 += bf_hi(r[q]); }
        }
        unsigned rsf = *(const unsigned*)(HB + (size_t)v * DD + c);
        float dv = dis[v];
        float o0 = fmaf(a0 + bf_lo(rsf), dv, b0);
        float o1 = fmaf(a1 + bf_hi(rsf), dv, b1);
        *(unsigned*)(AGG + (size_t)v * DD + c) = pack2bf(o0, o1);
        lsum0 += o0; lsum1 += o1;
        lsq0 += o0 * o0; lsq1 += o1 * o1;
    }
    atomicAdd(&s_sum[c], lsum0);
    atomicAdd(&s_sum[c + 1], lsum1);
    atomicAdd(&s_sq[c], lsq0);
    atomicAdd(&s_sq[c + 1], lsq1);
    __syncthreads();
    if (tid < 128) {
        float* slot = statsP + (size_t)(blockIdx.x & (NSLOT - 1)) * 256;
        atomicAdd(&slot[tid], s_sum[tid]);
        atomicAdd(&slot[128 + tid], s_sq[tid]);
    }
}

// ---------------- Pool (bf16 agg, BN3 fused from statsP) ----------------

__global__ __launch_bounds__(256) void pool_k(const u16* __restrict__ AGG,
                                              const int* __restrict__ batch,
                                              const float* __restrict__ statsP,
                                              const float* __restrict__ g,
                                              const float* __restrict__ be,
                                              float* __restrict__ P) {
    __shared__ float psc[128], psh[128];
    int tid = threadIdx.x;
    if (tid < 128) {
        float sum = 0.f, sq = 0.f;
#pragma unroll
        for (int s = 0; s < NSLOT; s++) {
            sum += statsP[(size_t)s * 256 + tid];
            sq  += statsP[(size_t)s * 256 + 128 + tid];
        }
        float mean = sum * (1.0f / NN);
        float var = sq * (1.0f / NN) - mean * mean;
        float scl = g[tid] / sqrtf(var + BN_EPS);
        psc[tid] = scl;
        psh[tid] = be[tid] - mean * scl;
    }
    __syncthreads();
    int lane = tid & 63;
    int wid = blockIdx.x * 4 + (tid >> 6);
    int nw = gridDim.x * 4;
    int c = lane * 2;
    float sc0 = psc[c], sc1 = psc[c + 1], sh0 = psh[c], sh1 = psh[c + 1];
    int chunk = (NN + nw - 1) / nw;
    int v0 = wid * chunk, v1 = v0 + chunk;
    if (v1 > NN) v1 = NN;
    if (v0 >= NN) return;
    int curb = batch[v0];
    float acc0 = 0.f, acc1 = 0.f;
    for (int v = v0; v < v1; v++) {
        int b = batch[v];
        if (b != curb) {
            atomicAdd(&P[curb * 128 + c], acc0);
            atomicAdd(&P[curb * 128 + c + 1], acc1);
            acc0 = 0.f; acc1 = 0.f; curb = b;
        }
        unsigned hv = *(const unsigned*)(AGG + (size_t)v * DD + c);
        acc0 += fmaxf(fmaf(bf_lo(hv), sc0, sh0), 0.f);
        acc1 += fmaxf(fmaf(bf_hi(hv), sc1, sh1), 0.f);
    }
    atomicAdd(&P[curb * 128 + c], acc0);
    atomicAdd(&P[curb * 128 + c + 1], acc1);
}

// ---------------- Head ----------------

__global__ __launch_bounds__(128) void head_k(const float* __restrict__ P,
                                              const float* __restrict__ Wm1,
                                              const float* __restrict__ bm1,
                                              const float* __restrict__ Wm2,
                                              const float* __restrict__ bm2,
                                              float* __restrict__ OUT) {
    __shared__ float prow[128];
    __shared__ float red[128];
    int g = blockIdx.x, t = threadIdx.x;
    prow[t] = P[g * 128 + t];
    __syncthreads();
    float acc = bm1[t];
#pragma unroll 8
    for (int i = 0; i < 128; i++) acc = fmaf(prow[i], Wm1[i * 128 + t], acc);
    red[t] = fmaxf(acc, 0.f) * Wm2[t];
    __syncthreads();
    for (int off = 64; off > 0; off >>= 1) {
        if (t < off) red[t] += red[t + off];
        __syncthreads();
    }
    if (t == 0) OUT[g] = red[0] + bm2[0];
}

// ---------------- Launch ----------------

extern "C" void kernel_launch(void* const* d_in, const int* in_sizes, int n_in,
                              void* d_out, int out_size, void* d_ws, size_t ws_size,
                              hipStream_t stream) {
    const float* x   = (const float*)d_in[0];
    const int*  ei   = (const int*)d_in[1];
    const int*  batch= (const int*)d_in[2];
    const float* W1  = (const float*)d_in[3];
    const float* b1  = (const float*)d_in[4];
    const float* g1  = (const float*)d_in[5];
    const float* be1 = (const float*)d_in[6];
    const float* W2  = (const float*)d_in[7];
    const float* b2  = (const float*)d_in[8];
    const float* g2  = (const float*)d_in[9];
    const float* be2 = (const float*)d_in[10];
    const float* W3  = (const float*)d_in[11];
    const float* b3  = (const float*)d_in[12];
    const float* g3  = (const float*)d_in[13];
    const float* be3 = (const float*)d_in[14];
    const float* Wm1 = (const float*)d_in[15];
    const float* bm1 = (const float*)d_in[16];
    const float* Wm2 = (const float*)d_in[17];
    const float* bm2 = (const float*)d_in[18];
    float* out = (float*)d_out;

    char* ws = (char*)d_ws;
    size_t off = 0;
    auto alloc = [&](size_t bytes) -> void* {
        void* p = ws + off;
        off = (off + bytes + 255) & ~(size_t)255;
        return p;
    };
    int*   fc    = (int*)alloc((size_t)NN * 4);
    float* dis   = (float*)alloc((size_t)NN * 4);
    u16*   ell   = (u16*)alloc((size_t)NN * ELLW * 2);
    u16*   hb    = (u16*)alloc((size_t)(NN + 1) * DD * 2);   // +1 zero row
    u16*   agg   = (u16*)alloc((size_t)NN * DD * 2);
    u16*   wt    = (u16*)alloc((size_t)3 * 2 * 16384 * 2);
    unsigned* buckets = (unsigned*)alloc((size_t)NBK * BKCAP * 4);
    // contiguous zero region: statsP (3*NSLOT*256*4) + p + bcnt
    float* statsP= (float*)alloc((size_t)3 * NSLOT * 256 * 4);
    float* p     = (float*)alloc((size_t)NG * DD * 4);
    int*   bcnt  = (int*)alloc((size_t)NBK * 4);

    const int* srcI = ei;
    const int* dstI = ei + NE;

    hipMemsetAsync(statsP, 0, (size_t)3 * NSLOT * 256 * 4 + (size_t)NG * DD * 4 + (size_t)NBK * 4, stream);

    binpass_k<<<P1_BLOCKS, 256, 0, stream>>>(srcI, dstI, bcnt, buckets);
    ellpass_k<<<NBK, 256, 0, stream>>>(bcnt, buckets, fc, dis, ell, hb);
    wprep_k<<<192, 256, 0, stream>>>(W1, W2, W3, wt);

    const int GB = (NN + 63) / 64;
    const size_t SL = (size_t)NSLOT * 256;

    // Layer 1 (fp32 input converted inline; no BN)
    mgemm_k<<<GB, 256, 0, stream>>>(x, nullptr, wt, nullptr, nullptr, nullptr, dis, hb, 0);
    gather_k<<<GATHER_BLOCKS, 256, 0, stream>>>(hb, dis, fc, ell, b1, agg, statsP);

    // Layer 2 (BN1 fused into preamble)
    mgemm_k<<<GB, 256, 0, stream>>>(nullptr, agg, wt + 2 * 16384, statsP, g1, be1, dis, hb, 1);
    gather_k<<<GATHER_BLOCKS, 256, 0, stream>>>(hb, dis, fc, ell, b2, agg, statsP + SL);

    // Layer 3 (BN2 fused)
    mgemm_k<<<GB, 256, 0, stream>>>(nullptr, agg, wt + 4 * 16384, statsP + SL, g2, be2, dis, hb, 1);
    gather_k<<<GATHER_BLOCKS, 256, 0, stream>>>(hb, dis, fc, ell, b3, agg, statsP + 2 * SL);

    // Pool (BN3 fused) + head
    pool_k<<<512, 256, 0, stream>>>(agg, batch, statsP + 2 * SL, g3, be3, p);
    head_k<<<NG, 128, 0, stream>>>(p, Wm1, bm1, Wm2, bm2, out);
}